// Round 2
// baseline (435.653 us; speedup 1.0000x reference)
//
#include <hip/hip_runtime.h>

typedef unsigned int u32;

#define BB 8
#define SS 2048
#define KK 16
#define RR 16
#define DIN 2048
#define DOUT 2048

// ---------------------------------------------------------------------------
// Kernel 1: mix the banks (all fp32).
//   Am[b][r][i] = sum_k alpha[b][k] * A_bank[k][r][i]
//   Bm[b][o][r] = sum_k alpha[b][k] * B_bank[k][o][r]
// ---------------------------------------------------------------------------
__global__ void __launch_bounds__(256) mix_kernel(
    const float* __restrict__ alpha,
    const float* __restrict__ A_bank,
    const float* __restrict__ B_bank,
    float* __restrict__ Am,
    float* __restrict__ Bm)
{
    int t = blockIdx.x * 256 + threadIdx.x;
    const int half = BB * RR * DIN;  // 262144
    if (t < half) {
        // t = (b*RR + r)*DIN + i   (i fastest -> coalesced)
        int i = t & (DIN - 1);
        int r = (t >> 11) & (RR - 1);
        int b = t >> 15;
        float acc = 0.f;
#pragma unroll
        for (int k = 0; k < KK; ++k)
            acc += alpha[b * KK + k] * A_bank[(k * RR + r) * DIN + i];
        Am[t] = acc;
    } else {
        int u = t - half;
        // u = (b*DOUT + o)*RR + r  (r fastest -> coalesced)
        int r = u & (RR - 1);
        int o = (u >> 4) & (DOUT - 1);
        int b = u >> 15;
        float acc = 0.f;
#pragma unroll
        for (int k = 0; k < KK; ++k)
            acc += alpha[b * KK + k] * B_bank[(k * DOUT + o) * RR + r];
        Bm[u] = acc;
    }
}

// ---------------------------------------------------------------------------
// Kernel 2: z[b][s][r] = sum_i Am[b][r][i] * h[b][s][i]   (fp32)
// Block = 256 thr (4 waves). Wave handles 8 s rows (2 groups of 4).
// Lanes span i (coalesced float4 loads). fp32 acc[4][16] in regs, then a
// log-tree cross-lane reduction (payload halves each step: 63 shfl/group).
// Grid: (S/32, B) = (64, 8).
// ---------------------------------------------------------------------------
__global__ void __launch_bounds__(256) z_kernel(
    const float* __restrict__ h,
    const float* __restrict__ Am,
    float* __restrict__ z)
{
    int b = blockIdx.y;
    int wave = threadIdx.x >> 6;
    int lane = threadIdx.x & 63;
    int sbase = blockIdx.x * 32 + wave * 8;
    const float* hb = h + (size_t)b * SS * DIN;
    const float* Ab = Am + (size_t)b * RR * DIN;

#pragma unroll
    for (int sg = 0; sg < 2; ++sg) {
        int s0 = sbase + sg * 4;
        float a[64];
#pragma unroll
        for (int v = 0; v < 64; ++v) a[v] = 0.f;

#pragma unroll
        for (int t = 0; t < 8; ++t) {
            int i0 = t * 256 + lane * 4;
            float4 hv[4];
#pragma unroll
            for (int j = 0; j < 4; ++j)
                hv[j] = *(const float4*)(hb + (size_t)(s0 + j) * DIN + i0);
#pragma unroll
            for (int r = 0; r < 16; ++r) {
                float4 av = *(const float4*)(Ab + r * DIN + i0);
#pragma unroll
                for (int j = 0; j < 4; ++j) {
                    a[j * 16 + r] += hv[j].x * av.x + hv[j].y * av.y
                                   + hv[j].z * av.z + hv[j].w * av.w;
                }
            }
        }

        // Cross-lane tree reduction: lane l ends with the full sum of value
        // index l (= j*16 + r). Payload halves each step.
#pragma unroll
        for (int off = 32; off >= 1; off >>= 1) {
            bool up = (lane & off) != 0;
#pragma unroll
            for (int v = 0; v < off; ++v) {
                float send = up ? a[v] : a[v + off];
                float keep = up ? a[v + off] : a[v];
                a[v] = keep + __shfl_xor(send, off, 64);
            }
        }
        // lane l -> z[b][s0 + l/16][l%16]: contiguous across lanes
        z[(size_t)(b * SS + s0) * RR + lane] = a[0];
    }
}

// ---------------------------------------------------------------------------
// Kernel 3: delta[b][s][o] = sum_r Bm[b][o][r] * z[b][s][r]   (fp32 out)
// Thread owns 4 contiguous o; Bm rows live in registers for whole s-tile.
// z[s][0:16] is block-uniform (scalarizable, L1). Coalesced float4 stores.
// Grid: (DOUT/1024, S/64, B) = (2, 32, 8).
// ---------------------------------------------------------------------------
__global__ void __launch_bounds__(256) delta_kernel(
    const float* __restrict__ z,
    const float* __restrict__ Bm,
    float* __restrict__ out)
{
    int b = blockIdx.z;
    int s0 = blockIdx.y * 64;
    int o0 = blockIdx.x * 1024 + threadIdx.x * 4;

    const float* wp = Bm + ((size_t)b * DOUT + o0) * RR;  // 64 contiguous floats
    float w[4][16];
#pragma unroll
    for (int j = 0; j < 4; ++j) {
#pragma unroll
        for (int q = 0; q < 4; ++q) {
            float4 p = *(const float4*)(wp + j * 16 + q * 4);
            w[j][q * 4 + 0] = p.x; w[j][q * 4 + 1] = p.y;
            w[j][q * 4 + 2] = p.z; w[j][q * 4 + 3] = p.w;
        }
    }

    const float* zp = z + (size_t)(b * SS + s0) * RR;
    float* op = out + ((size_t)b * SS + s0) * DOUT + o0;

    for (int s = 0; s < 64; ++s) {
        float4 z0 = *(const float4*)(zp + s * 16);
        float4 z1 = *(const float4*)(zp + s * 16 + 4);
        float4 z2 = *(const float4*)(zp + s * 16 + 8);
        float4 z3 = *(const float4*)(zp + s * 16 + 12);
        float zz[16] = {z0.x, z0.y, z0.z, z0.w, z1.x, z1.y, z1.z, z1.w,
                        z2.x, z2.y, z2.z, z2.w, z3.x, z3.y, z3.z, z3.w};
        float4 res;
        float rj[4];
#pragma unroll
        for (int j = 0; j < 4; ++j) {
            float acc = 0.f;
#pragma unroll
            for (int r = 0; r < 16; ++r) acc += w[j][r] * zz[r];
            rj[j] = acc;
        }
        res.x = rj[0]; res.y = rj[1]; res.z = rj[2]; res.w = rj[3];
        *(float4*)(op + (size_t)s * DOUT) = res;
    }
}

// ---------------------------------------------------------------------------
extern "C" void kernel_launch(void* const* d_in, const int* in_sizes, int n_in,
                              void* d_out, int out_size, void* d_ws, size_t ws_size,
                              hipStream_t stream)
{
    const float* h      = (const float*)d_in[0];   // [B][S][DIN]   fp32
    const float* alpha  = (const float*)d_in[1];   // [B][K]        fp32
    const float* A_bank = (const float*)d_in[2];   // [K][R][DIN]   fp32
    const float* B_bank = (const float*)d_in[3];   // [K][DOUT][R]  fp32
    float* out = (float*)d_out;                    // [B][S][DOUT]  fp32

    // workspace layout (5 MiB total):
    float* Am = (float*)d_ws;                      // [B][R][DIN]  fp32, 2 MiB
    float* Bm = Am + BB * RR * DIN;                // [B][DOUT][R] fp32, 2 MiB
    float* z  = Bm + BB * DOUT * RR;               // [B][S][R]    fp32, 1 MiB

    mix_kernel<<<2048, 256, 0, stream>>>(alpha, A_bank, B_bank, Am, Bm);
    z_kernel<<<dim3(64, 8), 256, 0, stream>>>(h, Am, z);
    delta_kernel<<<dim3(2, 32, 8), 256, 0, stream>>>(z, Bm, out);
}

// Round 4
// 257.016 us; speedup vs baseline: 1.6950x; 1.6950x over previous
//
#include <hip/hip_runtime.h>

typedef unsigned int u32;
typedef float f32x4 __attribute__((ext_vector_type(4)));

#define BB 8
#define SS 2048
#define KK 16
#define RR 16
#define DIN 2048
#define DOUT 2048

// ---------------------------------------------------------------------------
// Kernel 1: mix the banks (all fp32).
//   Am[b][r][i] = sum_k alpha[b][k] * A_bank[k][r][i]
//   Bm[b][o][r] = sum_k alpha[b][k] * B_bank[k][o][r]
// ---------------------------------------------------------------------------
__global__ void __launch_bounds__(256) mix_kernel(
    const float* __restrict__ alpha,
    const float* __restrict__ A_bank,
    const float* __restrict__ B_bank,
    float* __restrict__ Am,
    float* __restrict__ Bm)
{
    int t = blockIdx.x * 256 + threadIdx.x;
    const int half = BB * RR * DIN;  // 262144
    if (t < half) {
        // t = (b*RR + r)*DIN + i   (i fastest -> coalesced)
        int i = t & (DIN - 1);
        int r = (t >> 11) & (RR - 1);
        int b = t >> 15;
        float acc = 0.f;
#pragma unroll
        for (int k = 0; k < KK; ++k)
            acc += alpha[b * KK + k] * A_bank[(k * RR + r) * DIN + i];
        Am[t] = acc;
    } else {
        int u = t - half;
        // u = (b*DOUT + o)*RR + r  (r fastest -> coalesced)
        int r = u & (RR - 1);
        int o = (u >> 4) & (DOUT - 1);
        int b = u >> 15;
        float acc = 0.f;
#pragma unroll
        for (int k = 0; k < KK; ++k)
            acc += alpha[b * KK + k] * B_bank[(k * DOUT + o) * RR + r];
        Bm[u] = acc;
    }
}

// ---------------------------------------------------------------------------
// Kernel 2: z[b][s][r] = sum_i Am[b][r][i] * h[b][s][i]   (fp32)
// Wave owns 4 s rows; lanes span i (coalesced float4). acc[4][16]=64 regs.
// i-chunk loop is NOT unrolled (unroll 1) — round-1's unroll-8 put 8 chunks
// of loads in flight and spilled acc[] to scratch (VGPR=256, 183 MB scratch
// writes). Cap at 3 waves/EU (~168 VGPR) so the ~100-reg live set fits.
// Tree reduction: payload halves each step; lane l ends with sum of value
// index l (= j*16 + r); lane-contiguous store.
// Grid: (S/16, B) = (128, 8).
// ---------------------------------------------------------------------------
__global__ void __launch_bounds__(256, 3) z_kernel(
    const float* __restrict__ h,
    const float* __restrict__ Am,
    float* __restrict__ z)
{
    int b = blockIdx.y;
    int wid = threadIdx.x >> 6;
    int lane = threadIdx.x & 63;
    int s0 = blockIdx.x * 16 + wid * 4;
    const float* hb = h + (size_t)b * SS * DIN + (size_t)s0 * DIN;
    const float* Ab = Am + (size_t)b * RR * DIN;

    float a[64];
#pragma unroll
    for (int v = 0; v < 64; ++v) a[v] = 0.f;

#pragma unroll 1
    for (int t = 0; t < 8; ++t) {
        int i0 = t * 256 + lane * 4;
        float4 hv0 = *(const float4*)(hb + i0);
        float4 hv1 = *(const float4*)(hb + DIN + i0);
        float4 hv2 = *(const float4*)(hb + 2 * DIN + i0);
        float4 hv3 = *(const float4*)(hb + 3 * DIN + i0);
#pragma unroll
        for (int r = 0; r < 16; ++r) {
            float4 av = *(const float4*)(Ab + r * DIN + i0);
            a[0 * 16 + r] += hv0.x * av.x + hv0.y * av.y + hv0.z * av.z + hv0.w * av.w;
            a[1 * 16 + r] += hv1.x * av.x + hv1.y * av.y + hv1.z * av.z + hv1.w * av.w;
            a[2 * 16 + r] += hv2.x * av.x + hv2.y * av.y + hv2.z * av.z + hv2.w * av.w;
            a[3 * 16 + r] += hv3.x * av.x + hv3.y * av.y + hv3.z * av.z + hv3.w * av.w;
        }
    }

    // Cross-lane tree reduction, payload halving each step (63 shfl total).
#pragma unroll
    for (int off = 32; off >= 1; off >>= 1) {
        bool up = (lane & off) != 0;
#pragma unroll
        for (int v = 0; v < off; ++v) {
            float send = up ? a[v] : a[v + off];
            float keep = up ? a[v + off] : a[v];
            a[v] = keep + __shfl_xor(send, off, 64);
        }
    }
    // lane l -> z[b][s0 + l/16][l%16]: 64 contiguous floats across lanes
    z[(size_t)(b * SS + s0) * RR + lane] = a[0];
}

// ---------------------------------------------------------------------------
// Kernel 3: delta[b][s][o] = sum_r Bm[b][o][r] * z[b][s][r]   (fp32 out)
// Thread owns 4 contiguous o; Bm rows in registers for the whole 64-s tile.
// z[s][0:16] is wave-uniform (L1 broadcast). Nontemporal ext-vector stores
// (streamed output, no reuse). s-loop unroll 2 to bound register pressure.
// Grid: (DOUT/1024, S/64, B) = (2, 32, 8).
// ---------------------------------------------------------------------------
__global__ void __launch_bounds__(256, 4) delta_kernel(
    const float* __restrict__ z,
    const float* __restrict__ Bm,
    float* __restrict__ out)
{
    int b = blockIdx.z;
    int s0 = blockIdx.y * 64;
    int o0 = blockIdx.x * 1024 + threadIdx.x * 4;

    const float* wp = Bm + ((size_t)b * DOUT + o0) * RR;  // 64 contiguous floats
    float w[4][16];
#pragma unroll
    for (int j = 0; j < 4; ++j) {
#pragma unroll
        for (int q = 0; q < 4; ++q) {
            float4 p = *(const float4*)(wp + j * 16 + q * 4);
            w[j][q * 4 + 0] = p.x; w[j][q * 4 + 1] = p.y;
            w[j][q * 4 + 2] = p.z; w[j][q * 4 + 3] = p.w;
        }
    }

    const float* zp = z + (size_t)(b * SS + s0) * RR;
    float* op = out + ((size_t)b * SS + s0) * DOUT + o0;

#pragma unroll 2
    for (int s = 0; s < 64; ++s) {
        float4 z0 = *(const float4*)(zp + s * 16);
        float4 z1 = *(const float4*)(zp + s * 16 + 4);
        float4 z2 = *(const float4*)(zp + s * 16 + 8);
        float4 z3 = *(const float4*)(zp + s * 16 + 12);
        float zz[16] = {z0.x, z0.y, z0.z, z0.w, z1.x, z1.y, z1.z, z1.w,
                        z2.x, z2.y, z2.z, z2.w, z3.x, z3.y, z3.z, z3.w};
        float rj[4];
#pragma unroll
        for (int j = 0; j < 4; ++j) {
            float acc = 0.f;
#pragma unroll
            for (int r = 0; r < 16; ++r) acc += w[j][r] * zz[r];
            rj[j] = acc;
        }
        f32x4 res;
        res.x = rj[0]; res.y = rj[1]; res.z = rj[2]; res.w = rj[3];
        __builtin_nontemporal_store(res, (f32x4*)(op + (size_t)s * DOUT));
    }
}

// ---------------------------------------------------------------------------
extern "C" void kernel_launch(void* const* d_in, const int* in_sizes, int n_in,
                              void* d_out, int out_size, void* d_ws, size_t ws_size,
                              hipStream_t stream)
{
    const float* h      = (const float*)d_in[0];   // [B][S][DIN]   fp32
    const float* alpha  = (const float*)d_in[1];   // [B][K]        fp32
    const float* A_bank = (const float*)d_in[2];   // [K][R][DIN]   fp32
    const float* B_bank = (const float*)d_in[3];   // [K][DOUT][R]  fp32
    float* out = (float*)d_out;                    // [B][S][DOUT]  fp32

    // workspace layout (5 MiB total):
    float* Am = (float*)d_ws;                      // [B][R][DIN]  fp32, 2 MiB
    float* Bm = Am + BB * RR * DIN;                // [B][DOUT][R] fp32, 2 MiB
    float* z  = Bm + BB * DOUT * RR;               // [B][S][R]    fp32, 1 MiB

    mix_kernel<<<2048, 256, 0, stream>>>(alpha, A_bank, B_bank, Am, Bm);
    z_kernel<<<dim3(128, 8), 256, 0, stream>>>(h, Am, z);
    delta_kernel<<<dim3(2, 32, 8), 256, 0, stream>>>(z, Bm, out);
}